// Round 2
// baseline (418.023 us; speedup 1.0000x reference)
//
#include <hip/hip_runtime.h>

#define D_MODEL 4096
#define NEXP    64
#define NTOK    16384
#define NKS     128              // k-steps of 32: 4096/32

typedef _Float16 half8 __attribute__((ext_vector_type(8)));
typedef float    f32x4 __attribute__((ext_vector_type(4)));

// Dekker-style split of 8 fp32 into f16 hi + f16 lo planes (RTZ; lo catches residual)
__device__ __forceinline__ void split8(float4 a, float4 b, half8& hi, half8& lo) {
    auto h0 = __builtin_amdgcn_cvt_pkrtz(a.x, a.y);
    auto h1 = __builtin_amdgcn_cvt_pkrtz(a.z, a.w);
    auto h2 = __builtin_amdgcn_cvt_pkrtz(b.x, b.y);
    auto h3 = __builtin_amdgcn_cvt_pkrtz(b.z, b.w);
    hi[0] = static_cast<_Float16>(h0[0]); hi[1] = static_cast<_Float16>(h0[1]);
    hi[2] = static_cast<_Float16>(h1[0]); hi[3] = static_cast<_Float16>(h1[1]);
    hi[4] = static_cast<_Float16>(h2[0]); hi[5] = static_cast<_Float16>(h2[1]);
    hi[6] = static_cast<_Float16>(h3[0]); hi[7] = static_cast<_Float16>(h3[1]);
    float r0 = a.x - (float)h0[0], r1 = a.y - (float)h0[1];
    float r2 = a.z - (float)h1[0], r3 = a.w - (float)h1[1];
    float r4 = b.x - (float)h2[0], r5 = b.y - (float)h2[1];
    float r6 = b.z - (float)h3[0], r7 = b.w - (float)h3[1];
    auto l0 = __builtin_amdgcn_cvt_pkrtz(r0, r1);
    auto l1 = __builtin_amdgcn_cvt_pkrtz(r2, r3);
    auto l2 = __builtin_amdgcn_cvt_pkrtz(r4, r5);
    auto l3 = __builtin_amdgcn_cvt_pkrtz(r6, r7);
    lo[0] = static_cast<_Float16>(l0[0]); lo[1] = static_cast<_Float16>(l0[1]);
    lo[2] = static_cast<_Float16>(l1[0]); lo[3] = static_cast<_Float16>(l1[1]);
    lo[4] = static_cast<_Float16>(l2[0]); lo[5] = static_cast<_Float16>(l2[1]);
    lo[6] = static_cast<_Float16>(l3[0]); lo[7] = static_cast<_Float16>(l3[1]);
}

// ---- W prep: split fp32 W[d][e] into f16 hi/lo planes, laid out in exact
// B-fragment order: frag fi = ((ks*4 + tile)*2 + plane), 64 lanes x 16B each.
// Lane l of frag: expert = 16*tile + (l&15), k = ks*32 + (l>>4)*8 + j, j=0..7.
__global__ __launch_bounds__(256) void prep_w(const float* __restrict__ W,
                                              half8* __restrict__ ws) {
    const int gid  = blockIdx.x * 256 + threadIdx.x;   // 0..32767
    const int lane = gid & 63;
    const int fp   = gid >> 6;                         // 0..511 = ks*4 + tile
    const int t    = fp & 3;
    const int ks   = fp >> 2;
    const int e    = 16 * t + (lane & 15);
    const int k0   = ks * 32 + (lane >> 4) * 8;
    float4 a, b;
    a.x = W[(size_t)(k0 + 0) * NEXP + e];
    a.y = W[(size_t)(k0 + 1) * NEXP + e];
    a.z = W[(size_t)(k0 + 2) * NEXP + e];
    a.w = W[(size_t)(k0 + 3) * NEXP + e];
    b.x = W[(size_t)(k0 + 4) * NEXP + e];
    b.y = W[(size_t)(k0 + 5) * NEXP + e];
    b.z = W[(size_t)(k0 + 6) * NEXP + e];
    b.w = W[(size_t)(k0 + 7) * NEXP + e];
    half8 hi, lo;
    split8(a, b, hi, lo);
    ws[(size_t)(fp * 2 + 0) * 64 + lane] = hi;
    ws[(size_t)(fp * 2 + 1) * 64 + lane] = lo;
}

// ---- main: f16-split MFMA GEMM, 4-way K-split across the block's 4 waves.
// Register pipeline: x 4-deep (HBM latency), W 2-deep (L2 latency), static
// slot indexing via 4-stage unrolled inner loop; sched_barrier(0) after each
// stage's load-issue block prevents the scheduler from sinking loads to uses
// (round-0 evidence: VGPR_Count=56 => compiler de-pipelined the old idiom).
__global__ __launch_bounds__(256, 3) void router_mfma(
    const float* __restrict__ x, const int4* __restrict__ wf,
    const float* __restrict__ b, float* __restrict__ out)
{
    __shared__ float part[4][16][68];                  // [kquarter][token][expert(+pad)]
    const int tid  = threadIdx.x;
    const int lane = tid & 63;
    const int wv   = tid >> 6;                         // K-quarter index 0..3
    const int tok0 = blockIdx.x * 16;
    const int m    = lane & 15;                        // token row within tile
    const int q    = lane >> 4;                        // quad
    const float* __restrict__ xrow =
        x + (size_t)(tok0 + m) * D_MODEL + wv * 1024 + q * 8;
    const int4* __restrict__ wq = wf + (size_t)wv * 32 * 512 + lane;

    f32x4 acc[4] = {};                                 // 4 expert tiles x 16x16

    float4 xa0, xb0, xa1, xb1, xa2, xb2, xa3, xb3;     // x: 4-deep
    int4   wba[4][2], wbb[4][2];                       // W: 2-deep (A/B)

#define LDX(slot, j)                                                     \
    do {                                                                 \
        const float* _p = xrow + (j) * 32;                               \
        xa##slot = *(const float4*)_p;                                   \
        xb##slot = *(const float4*)(_p + 4);                             \
    } while (0)

#define LDW(buf, j)                                                      \
    do {                                                                 \
        const int _base = (j) * 512;                                     \
        _Pragma("unroll")                                                \
        for (int _t = 0; _t < 4; _t++) {                                 \
            buf[_t][0] = wq[_base + _t * 128];                           \
            buf[_t][1] = wq[_base + _t * 128 + 64];                      \
        }                                                                \
    } while (0)

#define CMP(aslot, wb)                                                   \
    do {                                                                 \
        half8 ahi, alo;                                                  \
        split8(xa##aslot, xb##aslot, ahi, alo);                          \
        __builtin_amdgcn_sched_barrier(0);                               \
        _Pragma("unroll")                                                \
        for (int _t = 0; _t < 4; _t++) {                                 \
            half8 bhi = __builtin_bit_cast(half8, wb[_t][0]);            \
            half8 blo = __builtin_bit_cast(half8, wb[_t][1]);            \
            acc[_t] = __builtin_amdgcn_mfma_f32_16x16x32_f16(ahi, bhi, acc[_t], 0, 0, 0); \
            acc[_t] = __builtin_amdgcn_mfma_f32_16x16x32_f16(ahi, blo, acc[_t], 0, 0, 0); \
            acc[_t] = __builtin_amdgcn_mfma_f32_16x16x32_f16(alo, bhi, acc[_t], 0, 0, 0); \
        }                                                                \
    } while (0)

    // prologue: x(0..3), W(0)
    LDX(0, 0); LDX(1, 1); LDX(2, 2); LDX(3, 3);
    LDW(wba, 0);

#pragma unroll 1
    for (int it = 0; it < 8; it++) {
        const int jb = it * 4;
        // stage 0: consume x0/W-A; issue W(j+1)->B, x(j+4)->slot0
        LDW(wbb, (jb + 1) & 31);
        { const int jx = (jb + 4) & 31; half8 h_, l_; (void)h_; (void)l_;
          // split BEFORE overwriting slot 0
          CMP(0, wba); LDX(0, jx); }
        // stage 1: consume x1/W-B; issue W(j+2)->A, x(j+5)->slot1
        LDW(wba, (jb + 2) & 31);
        { const int jx = (jb + 5) & 31; CMP(1, wbb); LDX(1, jx); }
        // stage 2
        LDW(wbb, (jb + 3) & 31);
        { const int jx = (jb + 6) & 31; CMP(2, wba); LDX(2, jx); }
        // stage 3
        LDW(wba, (jb + 4) & 31);
        { const int jx = (jb + 7) & 31; CMP(3, wbb); LDX(3, jx); }
    }
#undef LDX
#undef LDW
#undef CMP

    // C/D layout (verified m89/m91): col = lane&15 (expert), row = q*4 + reg (token)
#pragma unroll
    for (int t = 0; t < 4; t++)
#pragma unroll
        for (int r = 0; r < 4; r++)
            part[wv][q * 4 + r][t * 16 + m] = acc[t][r];   // 2-way bank alias: free
    __syncthreads();

    const float bias = b[lane];
    float* __restrict__ probs_out = out;
    float* __restrict__ top_out   = out + (size_t)NTOK * NEXP;
    float* __restrict__ idx_out   = top_out + (size_t)NTOK * 2;

    // each wave finishes 4 token rows: softmax + top-2 over 64 experts (lane=expert)
#pragma unroll 1
    for (int r2 = 0; r2 < 4; r2++) {
        const int row   = wv * 4 + r2;
        const int token = tok0 + row;
        float logit = part[0][row][lane] + part[1][row][lane]
                    + part[2][row][lane] + part[3][row][lane] + bias;

        float mx = logit;
#pragma unroll
        for (int off = 32; off; off >>= 1) mx = fmaxf(mx, __shfl_xor(mx, off, 64));
        float ex = expf(logit - mx);
        float s = ex;
#pragma unroll
        for (int off = 32; off; off >>= 1) s += __shfl_xor(s, off, 64);
        float p = ex / s;
        probs_out[(size_t)token * NEXP + lane] = p;

        // top-1 (lowest index wins ties, matching lax.top_k)
        float v = p; int idx = lane;
#pragma unroll
        for (int off = 32; off; off >>= 1) {
            float ov = __shfl_xor(v, off, 64);
            int   oi = __shfl_xor(idx, off, 64);
            if (ov > v || (ov == v && oi < idx)) { v = ov; idx = oi; }
        }
        const float v1 = v; const int i1 = idx;
        // top-2
        v = (lane == i1) ? -1.0f : p; idx = lane;
#pragma unroll
        for (int off = 32; off; off >>= 1) {
            float ov = __shfl_xor(v, off, 64);
            int   oi = __shfl_xor(idx, off, 64);
            if (ov > v || (ov == v && oi < idx)) { v = ov; idx = oi; }
        }
        const float v2 = v; const int i2 = idx;

        if (lane == 0) {
            const float dnm = v1 + v2 + 1e-9f;
            top_out[(size_t)token * 2 + 0] = v1 / dnm;
            top_out[(size_t)token * 2 + 1] = v2 / dnm;
            idx_out[(size_t)token * 2 + 0] = (float)i1;
            idx_out[(size_t)token * 2 + 1] = (float)i2;
        }
    }
}

// ---- fallback (no workspace): round-2 validated structure, W read natural layout ----
#define BK  128
#define BKP (BK + 4)
__device__ __forceinline__ float rl(float v, int l) {
    return __int_as_float(__builtin_amdgcn_readlane(__float_as_int(v), l));
}
__global__ __launch_bounds__(128) void router_fallback(
    const float* __restrict__ x, const float* __restrict__ W,
    const float* __restrict__ b, float* __restrict__ out)
{
    __shared__ float wt[NEXP * BKP];
    const int tid  = threadIdx.x;
    const int lane = tid & 63;
    const int wv   = __builtin_amdgcn_readfirstlane(tid >> 6);
    const int tok0 = blockIdx.x * 16 + wv * 8;
    const float* __restrict__ xw = x + (size_t)tok0 * D_MODEL;

    float2 xcur[8], xnxt[8];
#pragma unroll
    for (int t = 0; t < 8; t++)
        xcur[t] = *(const float2*)(xw + (size_t)t * D_MODEL + 2 * lane);
    float accm[8];
#pragma unroll
    for (int t = 0; t < 8; t++) accm[t] = 0.f;

    for (int c = 0; c < D_MODEL / BK; c++) {
        const int k0 = c * BK;
        if (c + 1 < D_MODEL / BK) {
#pragma unroll
            for (int t = 0; t < 8; t++)
                xnxt[t] = *(const float2*)(xw + (size_t)t * D_MODEL + (k0 + BK) + 2 * lane);
        }
#pragma unroll
        for (int i = 0; i < 16; i++) {
            int n  = i * 128 + tid;
            int dd = n >> 4;
            int e0 = (n & 15) * 4;
            float4 v = *(const float4*)(W + (size_t)(k0 + dd) * NEXP + e0);
            wt[(e0 + 0) * BKP + dd] = v.x;
            wt[(e0 + 1) * BKP + dd] = v.y;
            wt[(e0 + 2) * BKP + dd] = v.z;
            wt[(e0 + 3) * BKP + dd] = v.w;
        }
        __syncthreads();
        float acc[8];
#pragma unroll
        for (int t = 0; t < 8; t++) acc[t] = 0.f;
        const float* wl = &wt[lane * BKP];
#pragma unroll 4
        for (int kk = 0; kk < BK; kk += 4) {
            float4 w4 = *(const float4*)(wl + kk);
            const int l0 = kk >> 1;
#pragma unroll
            for (int t = 0; t < 8; t++) {
                float a = acc[t];
                a = fmaf(rl(xcur[t].x, l0    ), w4.x, a);
                a = fmaf(rl(xcur[t].y, l0    ), w4.y, a);
                a = fmaf(rl(xcur[t].x, l0 + 1), w4.z, a);
                a = fmaf(rl(xcur[t].y, l0 + 1), w4.w, a);
                acc[t] = a;
            }
        }
#pragma unroll
        for (int t = 0; t < 8; t++) accm[t] += acc[t];
        __syncthreads();
#pragma unroll
        for (int t = 0; t < 8; t++) xcur[t] = xnxt[t];
    }

    const float bias = b[lane];
    float* __restrict__ probs_out = out;
    float* __restrict__ top_out   = out + (size_t)NTOK * NEXP;
    float* __restrict__ idx_out   = top_out + (size_t)NTOK * 2;
#pragma unroll 1
    for (int t = 0; t < 8; t++) {
        const int token = tok0 + t;
        float logit = accm[t] + bias;
        float mx = logit;
#pragma unroll
        for (int off = 32; off; off >>= 1) mx = fmaxf(mx, __shfl_xor(mx, off, 64));
        float ex = expf(logit - mx);
        float s = ex;
#pragma unroll
        for (int off = 32; off; off >>= 1) s += __shfl_xor(s, off, 64);
        float p = ex / s;
        probs_out[(size_t)token * NEXP + lane] = p;
        float v = p; int idx = lane;
#pragma unroll
        for (int off = 32; off; off >>= 1) {
            float ov = __shfl_xor(v, off, 64);
            int   oi = __shfl_xor(idx, off, 64);
            if (ov > v || (ov == v && oi < idx)) { v = ov; idx = oi; }
        }
        const float v1 = v; const int i1 = idx;
        v = (lane == i1) ? -1.0f : p; idx = lane;
#pragma unroll
        for (int off = 32; off; off >>= 1) {
            float ov = __shfl_xor(v, off, 64);
            int   oi = __shfl_xor(idx, off, 64);
            if (ov > v || (ov == v && oi < idx)) { v = ov; idx = oi; }
        }
        const float v2 = v; const int i2 = idx;
        if (lane == 0) {
            const float dnm = v1 + v2 + 1e-9f;
            top_out[(size_t)token * 2 + 0] = v1 / dnm;
            top_out[(size_t)token * 2 + 1] = v2 / dnm;
            idx_out[(size_t)token * 2 + 0] = (float)i1;
            idx_out[(size_t)token * 2 + 1] = (float)i2;
        }
    }
}

extern "C" void kernel_launch(void* const* d_in, const int* in_sizes, int n_in,
                              void* d_out, int out_size, void* d_ws, size_t ws_size,
                              hipStream_t stream) {
    const float* x = (const float*)d_in[0];
    const float* W = (const float*)d_in[1];
    const float* b = (const float*)d_in[2];
    float* out = (float*)d_out;

    const size_t need = (size_t)NKS * 4 * 2 * 64 * 16;   // 1 MiB of f16 fragments
    if (ws_size >= need) {
        prep_w<<<128, 256, 0, stream>>>(W, (half8*)d_ws);
        router_mfma<<<NTOK / 16, 256, 0, stream>>>(x, (const int4*)d_ws, b, out);
    } else {
        router_fallback<<<NTOK / 16, 128, 0, stream>>>(x, W, b, out);
    }
}

// Round 4
// 391.957 us; speedup vs baseline: 1.0665x; 1.0665x over previous
//
#include <hip/hip_runtime.h>

#define D_MODEL 4096
#define NEXP    64
#define NTOK    16384
#define NKS     128              // k-steps of 32: 4096/32

typedef _Float16 half8 __attribute__((ext_vector_type(8)));
typedef float    f32x4 __attribute__((ext_vector_type(4)));

// Dekker-style split of 8 fp32 into f16 hi + f16 lo planes (RTZ; lo catches residual)
__device__ __forceinline__ void split8(float4 a, float4 b, half8& hi, half8& lo) {
    auto h0 = __builtin_amdgcn_cvt_pkrtz(a.x, a.y);
    auto h1 = __builtin_amdgcn_cvt_pkrtz(a.z, a.w);
    auto h2 = __builtin_amdgcn_cvt_pkrtz(b.x, b.y);
    auto h3 = __builtin_amdgcn_cvt_pkrtz(b.z, b.w);
    hi[0] = static_cast<_Float16>(h0[0]); hi[1] = static_cast<_Float16>(h0[1]);
    hi[2] = static_cast<_Float16>(h1[0]); hi[3] = static_cast<_Float16>(h1[1]);
    hi[4] = static_cast<_Float16>(h2[0]); hi[5] = static_cast<_Float16>(h2[1]);
    hi[6] = static_cast<_Float16>(h3[0]); hi[7] = static_cast<_Float16>(h3[1]);
    float r0 = a.x - (float)h0[0], r1 = a.y - (float)h0[1];
    float r2 = a.z - (float)h1[0], r3 = a.w - (float)h1[1];
    float r4 = b.x - (float)h2[0], r5 = b.y - (float)h2[1];
    float r6 = b.z - (float)h3[0], r7 = b.w - (float)h3[1];
    auto l0 = __builtin_amdgcn_cvt_pkrtz(r0, r1);
    auto l1 = __builtin_amdgcn_cvt_pkrtz(r2, r3);
    auto l2 = __builtin_amdgcn_cvt_pkrtz(r4, r5);
    auto l3 = __builtin_amdgcn_cvt_pkrtz(r6, r7);
    lo[0] = static_cast<_Float16>(l0[0]); lo[1] = static_cast<_Float16>(l0[1]);
    lo[2] = static_cast<_Float16>(l1[0]); lo[3] = static_cast<_Float16>(l1[1]);
    lo[4] = static_cast<_Float16>(l2[0]); lo[5] = static_cast<_Float16>(l2[1]);
    lo[6] = static_cast<_Float16>(l3[0]); lo[7] = static_cast<_Float16>(l3[1]);
}

// async global->LDS DMA, 16 B/lane: global src is per-lane, LDS dest is
// wave-uniform base + lane*16 (compiler cannot de-pipeline a DMA).
__device__ __forceinline__ void dma16(const float* g, float* l) {
    __builtin_amdgcn_global_load_lds(
        (const __attribute__((address_space(1))) unsigned int*)g,
        (__attribute__((address_space(3))) unsigned int*)l,
        16, 0, 0);
}

// ---- W prep: split fp32 W[d][e] into f16 hi/lo planes, laid out in exact
// B-fragment order: frag fi = ((ks*4 + tile)*2 + plane), 64 lanes x 16B each.
// Lane l of frag: expert = 16*tile + (l&15), k = ks*32 + (l>>4)*8 + j, j=0..7.
__global__ __launch_bounds__(256) void prep_w(const float* __restrict__ W,
                                              half8* __restrict__ ws) {
    const int gid  = blockIdx.x * 256 + threadIdx.x;   // 0..32767
    const int lane = gid & 63;
    const int fp   = gid >> 6;                         // 0..511 = ks*4 + tile
    const int t    = fp & 3;
    const int ks   = fp >> 2;
    const int e    = 16 * t + (lane & 15);
    const int k0   = ks * 32 + (lane >> 4) * 8;
    float4 a, b;
    a.x = W[(size_t)(k0 + 0) * NEXP + e];
    a.y = W[(size_t)(k0 + 1) * NEXP + e];
    a.z = W[(size_t)(k0 + 2) * NEXP + e];
    a.w = W[(size_t)(k0 + 3) * NEXP + e];
    b.x = W[(size_t)(k0 + 4) * NEXP + e];
    b.y = W[(size_t)(k0 + 5) * NEXP + e];
    b.z = W[(size_t)(k0 + 6) * NEXP + e];
    b.w = W[(size_t)(k0 + 7) * NEXP + e];
    half8 hi, lo;
    split8(a, b, hi, lo);
    ws[(size_t)(fp * 2 + 0) * 64 + lane] = hi;
    ws[(size_t)(fp * 2 + 1) * 64 + lane] = lo;
}

// ---- main: f16-split MFMA GEMM, 4-way K-split across the block's 4 waves.
// x path: async DMA into wave-private LDS, batches of 4 k-steps (512 B/row
// contiguous bursts -> DRAM page locality), counted vmcnt(8) so next batch's
// DMAs stay in flight under current batch's compute. Per-(block,wave) k-phase
// rotation decorrelates DRAM channel access chip-wide.
__global__ __launch_bounds__(256, 2) void router_mfma(
    const float* __restrict__ x, const int4* __restrict__ wf,
    const float* __restrict__ b, float* __restrict__ out)
{
    __shared__ float lds[4][4096];   // 64 KB: per-wave 16 KB x-staging; reused for logits
    const int tid  = threadIdx.x;
    const int lane = tid & 63;
    const int wv   = tid >> 6;                         // K-quarter index 0..3
    const int tok0 = blockIdx.x * 16;
    const int m    = lane & 15;                        // token row within tile
    const int q    = lane >> 4;                        // quad
    const float* __restrict__ xrow =
        x + (size_t)(tok0 + m) * D_MODEL + wv * 1024 + q * 8;
    const int4* __restrict__ wq = wf + (size_t)wv * 32 * 512 + lane;
    float* __restrict__ xs = lds[wv];

    const int rot = (blockIdx.x ^ wv) & 7;             // k-phase decorrelation

    f32x4 acc[4] = {};                                 // 4 expert tiles x 16x16
    int4  wba[4][2], wbb[4][2];                        // W: 2-deep A/B

    auto jof = [&](int bb) { return ((bb + rot) & 7) * 4; };

    // DMA one batch (4 k-steps) of x into buffer buf: 8 instrs, lane-linear dest.
    // Per row this requests 512 B of consecutive addresses back-to-back.
    auto stage = [&](int bb, int buf) {
        const int j0 = jof(bb);
        float* dst = xs + buf * 2048;
#pragma unroll
        for (int s = 0; s < 4; s++) {
            const float* src = xrow + (size_t)(j0 + s) * 32;
            dma16(src,     dst + (s * 2 + 0) * 256);
            dma16(src + 4, dst + (s * 2 + 1) * 256);
        }
    };
    auto ldw = [&](int4 (&w)[4][2], int j) {
        const int base = j * 512;
#pragma unroll
        for (int t = 0; t < 4; t++) {
            w[t][0] = wq[base + t * 128];
            w[t][1] = wq[base + t * 128 + 64];
        }
    };
    auto cmp = [&](int buf, int slot, int4 (&wb)[4][2]) {
        const float* px = xs + buf * 2048 + slot * 512 + lane * 4;
        float4 xa = *(const float4*)px;          // ds_read_b128, conflict-free
        float4 xb = *(const float4*)(px + 256);
        half8 ahi, alo;
        split8(xa, xb, ahi, alo);
#pragma unroll
        for (int t = 0; t < 4; t++) {
            half8 bhi = __builtin_bit_cast(half8, wb[t][0]);
            half8 blo = __builtin_bit_cast(half8, wb[t][1]);
            acc[t] = __builtin_amdgcn_mfma_f32_16x16x32_f16(ahi, bhi, acc[t], 0, 0, 0);
            acc[t] = __builtin_amdgcn_mfma_f32_16x16x32_f16(ahi, blo, acc[t], 0, 0, 0);
            acc[t] = __builtin_amdgcn_mfma_f32_16x16x32_f16(alo, bhi, acc[t], 0, 0, 0);
        }
    };

    // prologue
    stage(0, 0);
    ldw(wba, jof(0));

#pragma unroll 1
    for (int bb = 0; bb < 8; bb++) {
        const int buf = bb & 1;
        if (bb < 7) {
            stage(bb + 1, buf ^ 1);
            // 8 newest outstanding = next batch's DMAs; everything older
            // (this batch's DMAs + stray W loads) has completed. Register W
            // loads are additionally protected by compiler waitcnts.
            asm volatile("s_waitcnt vmcnt(8)" ::: "memory");
        } else {
            asm volatile("s_waitcnt vmcnt(0)" ::: "memory");
        }
        __builtin_amdgcn_sched_barrier(0);
        const int j0 = jof(bb);
        const int jn = jof((bb + 1) & 7);   // bb=7: redundant reload, harmless
        ldw(wbb, j0 + 1); cmp(buf, 0, wba);
        ldw(wba, j0 + 2); cmp(buf, 1, wbb);
        ldw(wbb, j0 + 3); cmp(buf, 2, wba);
        ldw(wba, jn);     cmp(buf, 3, wbb);
    }

    // C/D layout (verified m89/m91): col = lane&15 (expert), row = q*4 + reg (token)
    // Write partials into this wave's own (now dead) staging region: [row][68] floats.
#pragma unroll
    for (int t = 0; t < 4; t++)
#pragma unroll
        for (int r = 0; r < 4; r++)
            xs[(q * 4 + r) * 68 + t * 16 + m] = acc[t][r];
    __syncthreads();

    const float bias = b[lane];
    float* __restrict__ probs_out = out;
    float* __restrict__ top_out   = out + (size_t)NTOK * NEXP;
    float* __restrict__ idx_out   = top_out + (size_t)NTOK * 2;

    // each wave finishes 4 token rows: softmax + top-2 over 64 experts (lane=expert)
#pragma unroll 1
    for (int r2 = 0; r2 < 4; r2++) {
        const int row   = wv * 4 + r2;
        const int token = tok0 + row;
        float logit = lds[0][row * 68 + lane] + lds[1][row * 68 + lane]
                    + lds[2][row * 68 + lane] + lds[3][row * 68 + lane] + bias;

        float mx = logit;
#pragma unroll
        for (int off = 32; off; off >>= 1) mx = fmaxf(mx, __shfl_xor(mx, off, 64));
        float ex = expf(logit - mx);
        float s = ex;
#pragma unroll
        for (int off = 32; off; off >>= 1) s += __shfl_xor(s, off, 64);
        float p = ex / s;
        probs_out[(size_t)token * NEXP + lane] = p;

        // top-1 (lowest index wins ties, matching lax.top_k)
        float v = p; int idx = lane;
#pragma unroll
        for (int off = 32; off; off >>= 1) {
            float ov = __shfl_xor(v, off, 64);
            int   oi = __shfl_xor(idx, off, 64);
            if (ov > v || (ov == v && oi < idx)) { v = ov; idx = oi; }
        }
        const float v1 = v; const int i1 = idx;
        // top-2
        v = (lane == i1) ? -1.0f : p; idx = lane;
#pragma unroll
        for (int off = 32; off; off >>= 1) {
            float ov = __shfl_xor(v, off, 64);
            int   oi = __shfl_xor(idx, off, 64);
            if (ov > v || (ov == v && oi < idx)) { v = ov; idx = oi; }
        }
        const float v2 = v; const int i2 = idx;

        if (lane == 0) {
            const float dnm = v1 + v2 + 1e-9f;
            top_out[(size_t)token * 2 + 0] = v1 / dnm;
            top_out[(size_t)token * 2 + 1] = v2 / dnm;
            idx_out[(size_t)token * 2 + 0] = (float)i1;
            idx_out[(size_t)token * 2 + 1] = (float)i2;
        }
    }
}

// ---- fallback (no workspace): validated structure, W read natural layout ----
#define BK  128
#define BKP (BK + 4)
__device__ __forceinline__ float rl(float v, int l) {
    return __int_as_float(__builtin_amdgcn_readlane(__float_as_int(v), l));
}
__global__ __launch_bounds__(128) void router_fallback(
    const float* __restrict__ x, const float* __restrict__ W,
    const float* __restrict__ b, float* __restrict__ out)
{
    __shared__ float wt[NEXP * BKP];
    const int tid  = threadIdx.x;
    const int lane = tid & 63;
    const int wv   = __builtin_amdgcn_readfirstlane(tid >> 6);
    const int tok0 = blockIdx.x * 16 + wv * 8;
    const float* __restrict__ xw = x + (size_t)tok0 * D_MODEL;

    float2 xcur[8], xnxt[8];
#pragma unroll
    for (int t = 0; t < 8; t++)
        xcur[t] = *(const float2*)(xw + (size_t)t * D_MODEL + 2 * lane);
    float accm[8];
#pragma unroll
    for (int t = 0; t < 8; t++) accm[t] = 0.f;

    for (int c = 0; c < D_MODEL / BK; c++) {
        const int k0 = c * BK;
        if (c + 1 < D_MODEL / BK) {
#pragma unroll
            for (int t = 0; t < 8; t++)
                xnxt[t] = *(const float2*)(xw + (size_t)t * D_MODEL + (k0 + BK) + 2 * lane);
        }
#pragma unroll
        for (int i = 0; i < 16; i++) {
            int n  = i * 128 + tid;
            int dd = n >> 4;
            int e0 = (n & 15) * 4;
            float4 v = *(const float4*)(W + (size_t)(k0 + dd) * NEXP + e0);
            wt[(e0 + 0) * BKP + dd] = v.x;
            wt[(e0 + 1) * BKP + dd] = v.y;
            wt[(e0 + 2) * BKP + dd] = v.z;
            wt[(e0 + 3) * BKP + dd] = v.w;
        }
        __syncthreads();
        float acc[8];
#pragma unroll
        for (int t = 0; t < 8; t++) acc[t] = 0.f;
        const float* wl = &wt[lane * BKP];
#pragma unroll 4
        for (int kk = 0; kk < BK; kk += 4) {
            float4 w4 = *(const float4*)(wl + kk);
            const int l0 = kk >> 1;
#pragma unroll
            for (int t = 0; t < 8; t++) {
                float a = acc[t];
                a = fmaf(rl(xcur[t].x, l0    ), w4.x, a);
                a = fmaf(rl(xcur[t].y, l0    ), w4.y, a);
                a = fmaf(rl(xcur[t].x, l0 + 1), w4.z, a);
                a = fmaf(rl(xcur[t].y, l0 + 1), w4.w, a);
                acc[t] = a;
            }
        }
#pragma unroll
        for (int t = 0; t < 8; t++) accm[t] += acc[t];
        __syncthreads();
#pragma unroll
        for (int t = 0; t < 8; t++) xcur[t] = xnxt[t];
    }

    const float bias = b[lane];
    float* __restrict__ probs_out = out;
    float* __restrict__ top_out   = out + (size_t)NTOK * NEXP;
    float* __restrict__ idx_out   = top_out + (size_t)NTOK * 2;
#pragma unroll 1
    for (int t = 0; t < 8; t++) {
        const int token = tok0 + t;
        float logit = accm[t] + bias;
        float mx = logit;
#pragma unroll
        for (int off = 32; off; off >>= 1) mx = fmaxf(mx, __shfl_xor(mx, off, 64));
        float ex = expf(logit - mx);
        float s = ex;
#pragma unroll
        for (int off = 32; off; off >>= 1) s += __shfl_xor(s, off, 64);
        float p = ex / s;
        probs_out[(size_t)token * NEXP + lane] = p;
        float v = p; int idx = lane;
#pragma unroll
        for (int off = 32; off; off >>= 1) {
            float ov = __shfl_xor(v, off, 64);
            int   oi = __shfl_xor(idx, off, 64);
            if (ov > v || (ov == v && oi < idx)) { v = ov; idx = oi; }
        }
        const float v1 = v; const int i1 = idx;
        v = (lane == i1) ? -1.0f : p; idx = lane;
#pragma unroll
        for (int off = 32; off; off >>= 1) {
            float ov = __shfl_xor(v, off, 64);
            int   oi = __shfl_xor(idx, off, 64);
            if (ov > v || (ov == v && oi < idx)) { v = ov; idx = oi; }
        }
        const float v2 = v; const int i2 = idx;
        if (lane == 0) {
            const float dnm = v1 + v2 + 1e-9f;
            top_out[(size_t)token * 2 + 0] = v1 / dnm;
            top_out[(size_t)token * 2 + 1] = v2 / dnm;
            idx_out[(size_t)token * 2 + 0] = (float)i1;
            idx_out[(size_t)token * 2 + 1] = (float)i2;
        }
    }
}

extern "C" void kernel_launch(void* const* d_in, const int* in_sizes, int n_in,
                              void* d_out, int out_size, void* d_ws, size_t ws_size,
                              hipStream_t stream) {
    const float* x = (const float*)d_in[0];
    const float* W = (const float*)d_in[1];
    const float* b = (const float*)d_in[2];
    float* out = (float*)d_out;

    const size_t need = (size_t)NKS * 4 * 2 * 64 * 16;   // 1 MiB of f16 fragments
    if (ws_size >= need) {
        prep_w<<<128, 256, 0, stream>>>(W, (half8*)d_ws);
        router_mfma<<<NTOK / 16, 256, 0, stream>>>(x, (const int4*)d_ws, b, out);
    } else {
        router_fallback<<<NTOK / 16, 128, 0, stream>>>(x, W, b, out);
    }
}

// Round 5
// 385.259 us; speedup vs baseline: 1.0850x; 1.0174x over previous
//
#include <hip/hip_runtime.h>

#define D_MODEL 4096
#define NEXP    64
#define NTOK    16384
#define NKS     128              // k-steps of 32: 4096/32

typedef _Float16 half8 __attribute__((ext_vector_type(8)));
typedef float    f32x4 __attribute__((ext_vector_type(4)));

// Dekker-style split of 8 fp32 into f16 hi + f16 lo planes (RTZ; lo catches residual)
__device__ __forceinline__ void split8(float4 a, float4 b, half8& hi, half8& lo) {
    auto h0 = __builtin_amdgcn_cvt_pkrtz(a.x, a.y);
    auto h1 = __builtin_amdgcn_cvt_pkrtz(a.z, a.w);
    auto h2 = __builtin_amdgcn_cvt_pkrtz(b.x, b.y);
    auto h3 = __builtin_amdgcn_cvt_pkrtz(b.z, b.w);
    hi[0] = static_cast<_Float16>(h0[0]); hi[1] = static_cast<_Float16>(h0[1]);
    hi[2] = static_cast<_Float16>(h1[0]); hi[3] = static_cast<_Float16>(h1[1]);
    hi[4] = static_cast<_Float16>(h2[0]); hi[5] = static_cast<_Float16>(h2[1]);
    hi[6] = static_cast<_Float16>(h3[0]); hi[7] = static_cast<_Float16>(h3[1]);
    float r0 = a.x - (float)h0[0], r1 = a.y - (float)h0[1];
    float r2 = a.z - (float)h1[0], r3 = a.w - (float)h1[1];
    float r4 = b.x - (float)h2[0], r5 = b.y - (float)h2[1];
    float r6 = b.z - (float)h3[0], r7 = b.w - (float)h3[1];
    auto l0 = __builtin_amdgcn_cvt_pkrtz(r0, r1);
    auto l1 = __builtin_amdgcn_cvt_pkrtz(r2, r3);
    auto l2 = __builtin_amdgcn_cvt_pkrtz(r4, r5);
    auto l3 = __builtin_amdgcn_cvt_pkrtz(r6, r7);
    lo[0] = static_cast<_Float16>(l0[0]); lo[1] = static_cast<_Float16>(l0[1]);
    lo[2] = static_cast<_Float16>(l1[0]); lo[3] = static_cast<_Float16>(l1[1]);
    lo[4] = static_cast<_Float16>(l2[0]); lo[5] = static_cast<_Float16>(l2[1]);
    lo[6] = static_cast<_Float16>(l3[0]); lo[7] = static_cast<_Float16>(l3[1]);
}

// async global->LDS DMA, 16 B/lane: global src is per-lane, LDS dest is
// wave-uniform base + lane*16.
__device__ __forceinline__ void dma16(const float* g, float* l) {
    __builtin_amdgcn_global_load_lds(
        (const __attribute__((address_space(1))) unsigned int*)g,
        (__attribute__((address_space(3))) unsigned int*)l,
        16, 0, 0);
}

// ---- W prep: split fp32 W[d][e] into f16 hi/lo planes, laid out in exact
// B-fragment order: frag fi = ((ks*4 + tile)*2 + plane), 64 lanes x 16B each.
// Lane l of frag: expert = 16*tile + (l&15), k = ks*32 + (l>>4)*8 + j, j=0..7.
__global__ __launch_bounds__(256) void prep_w(const float* __restrict__ W,
                                              half8* __restrict__ ws) {
    const int gid  = blockIdx.x * 256 + threadIdx.x;   // 0..32767
    const int lane = gid & 63;
    const int fp   = gid >> 6;                         // 0..511 = ks*4 + tile
    const int t    = fp & 3;
    const int ks   = fp >> 2;
    const int e    = 16 * t + (lane & 15);
    const int k0   = ks * 32 + (lane >> 4) * 8;
    float4 a, b;
    a.x = W[(size_t)(k0 + 0) * NEXP + e];
    a.y = W[(size_t)(k0 + 1) * NEXP + e];
    a.z = W[(size_t)(k0 + 2) * NEXP + e];
    a.w = W[(size_t)(k0 + 3) * NEXP + e];
    b.x = W[(size_t)(k0 + 4) * NEXP + e];
    b.y = W[(size_t)(k0 + 5) * NEXP + e];
    b.z = W[(size_t)(k0 + 6) * NEXP + e];
    b.w = W[(size_t)(k0 + 7) * NEXP + e];
    half8 hi, lo;
    split8(a, b, hi, lo);
    ws[(size_t)(fp * 2 + 0) * 64 + lane] = hi;
    ws[(size_t)(fp * 2 + 1) * 64 + lane] = lo;
}

// ---- main: f16-split MFMA GEMM. Block = 32 tokens x 4 K-quarter waves.
// Each wave: TWO 16-token A-tiles over its 1024-k quarter -> same W bytes feed
// 2x the MFMAs (halves W line-traffic, the dominant per-CU request stream).
// x via DMA batches of 2 k-steps, double-buffered, counted vmcnt(16).
__global__ __launch_bounds__(256, 2) void router_mfma(
    const float* __restrict__ x, const int4* __restrict__ wf,
    const float* __restrict__ b, float* __restrict__ out)
{
    __shared__ float lds[4][4096];   // 64 KB: per-wave 16 KB x-staging; reused for partials
    const int tid  = threadIdx.x;
    const int lane = tid & 63;
    const int wv   = tid >> 6;                         // K-quarter index 0..3
    const int tok0 = blockIdx.x * 32;
    const int m    = lane & 15;                        // token row within tile
    const int q    = lane >> 4;                        // quad
    const int4* __restrict__ wq = wf + (size_t)wv * 32 * 512 + lane;
    float* __restrict__ xs = lds[wv];

    const int rot = (blockIdx.x ^ (wv << 2)) & 15;     // k-phase decorrelation

    // per-lane DMA source bases, one per DMA index d = tt*2 + h:
    // row = tok0 + tt*16 + m ; within-row float = wv*1024 + j*32 + h*16 + q*4
    const float* xsrc[4];
#pragma unroll
    for (int d = 0; d < 4; d++) {
        const int tt = d >> 1, h = d & 1;
        xsrc[d] = x + (size_t)(tok0 + tt * 16 + m) * D_MODEL
                    + wv * 1024 + h * 16 + q * 4;
    }

    f32x4 acc[2][4] = {};                              // [token-tile][expert-tile]
    int4  wba[4][2], wbb[4][2];                        // W: 2-deep A/B

    auto jof = [&](int bb) { return ((bb + rot) & 15) * 2; };

    // DMA one batch (2 k-steps) of x: 8 instrs, 8 KB, lane-linear dest.
    auto stage = [&](int bb, int buf) {
        const int j0 = jof(bb);
        float* dst = xs + buf * 2048;
#pragma unroll
        for (int s = 0; s < 2; s++)
#pragma unroll
            for (int d = 0; d < 4; d++)
                dma16(xsrc[d] + (size_t)(j0 + s) * 32, dst + s * 1024 + d * 256);
    };
    auto ldw = [&](int4 (&w)[4][2], int j) {
        const int base = j * 512;
#pragma unroll
        for (int t = 0; t < 4; t++) {
            w[t][0] = wq[base + t * 128];
            w[t][1] = wq[base + t * 128 + 64];
        }
    };
    // one k-step for both token-tiles: 2x split8 + 24 MFMA on shared W regs
    auto cmp = [&](int buf, int s, int4 (&wb)[4][2]) {
#pragma unroll
        for (int tt = 0; tt < 2; tt++) {
            const float* px = xs + buf * 2048 + s * 1024
                            + (tt * 2 + (q >> 1)) * 256 + (q & 1) * 128 + m * 4;
            float4 xa = *(const float4*)px;        // ds_read_b128, conflict-free
            float4 xb = *(const float4*)(px + 64);
            half8 ahi, alo;
            split8(xa, xb, ahi, alo);
#pragma unroll
            for (int t = 0; t < 4; t++) {
                half8 bhi = __builtin_bit_cast(half8, wb[t][0]);
                half8 blo = __builtin_bit_cast(half8, wb[t][1]);
                acc[tt][t] = __builtin_amdgcn_mfma_f32_16x16x32_f16(ahi, bhi, acc[tt][t], 0, 0, 0);
                acc[tt][t] = __builtin_amdgcn_mfma_f32_16x16x32_f16(ahi, blo, acc[tt][t], 0, 0, 0);
                acc[tt][t] = __builtin_amdgcn_mfma_f32_16x16x32_f16(alo, bhi, acc[tt][t], 0, 0, 0);
            }
        }
    };

    // prologue
    stage(0, 0);
    ldw(wba, jof(0));

#pragma unroll 1
    for (int bb = 0; bb < 16; bb++) {                  // 16 batches x 2 k-steps
        const int buf = bb & 1;
        if (bb < 15) {
            stage(bb + 1, buf ^ 1);
            // 16 newest = wba(8) + next batch's DMAs(8); everything older —
            // in particular THIS batch's DMAs — has completed. Register W
            // loads are additionally protected by compiler waitcnts at use.
            asm volatile("s_waitcnt vmcnt(16)" ::: "memory");
        } else {
            asm volatile("s_waitcnt vmcnt(0)" ::: "memory");
        }
        __builtin_amdgcn_sched_barrier(0);
        const int j0 = jof(bb);
        const int jn = jof((bb + 1) & 15);  // bb=15: redundant reload, harmless
        ldw(wbb, j0 + 1); cmp(buf, 0, wba);
        ldw(wba, jn);     cmp(buf, 1, wbb);
    }

    // C/D layout (verified m89/m91): col = lane&15 (expert), row = q*4 + reg.
    // Partials into this wave's (now dead) staging region: [32 rows][68].
#pragma unroll
    for (int tt = 0; tt < 2; tt++)
#pragma unroll
        for (int t = 0; t < 4; t++)
#pragma unroll
            for (int r = 0; r < 4; r++)
                xs[(tt * 16 + q * 4 + r) * 68 + t * 16 + m] = acc[tt][t][r];
    __syncthreads();

    const float bias = b[lane];
    float* __restrict__ probs_out = out;
    float* __restrict__ top_out   = out + (size_t)NTOK * NEXP;
    float* __restrict__ idx_out   = top_out + (size_t)NTOK * 2;

    // each wave finishes 8 token rows: softmax + top-2 over 64 experts
#pragma unroll 1
    for (int r2 = 0; r2 < 8; r2++) {
        const int row   = wv * 8 + r2;
        const int token = tok0 + row;
        float logit = lds[0][row * 68 + lane] + lds[1][row * 68 + lane]
                    + lds[2][row * 68 + lane] + lds[3][row * 68 + lane] + bias;

        float mx = logit;
#pragma unroll
        for (int off = 32; off; off >>= 1) mx = fmaxf(mx, __shfl_xor(mx, off, 64));
        float ex = expf(logit - mx);
        float s = ex;
#pragma unroll
        for (int off = 32; off; off >>= 1) s += __shfl_xor(s, off, 64);
        float p = ex / s;
        probs_out[(size_t)token * NEXP + lane] = p;

        // top-1 (lowest index wins ties, matching lax.top_k)
        float v = p; int idx = lane;
#pragma unroll
        for (int off = 32; off; off >>= 1) {
            float ov = __shfl_xor(v, off, 64);
            int   oi = __shfl_xor(idx, off, 64);
            if (ov > v || (ov == v && oi < idx)) { v = ov; idx = oi; }
        }
        const float v1 = v; const int i1 = idx;
        // top-2
        v = (lane == i1) ? -1.0f : p; idx = lane;
#pragma unroll
        for (int off = 32; off; off >>= 1) {
            float ov = __shfl_xor(v, off, 64);
            int   oi = __shfl_xor(idx, off, 64);
            if (ov > v || (ov == v && oi < idx)) { v = ov; idx = oi; }
        }
        const float v2 = v; const int i2 = idx;

        if (lane == 0) {
            const float dnm = v1 + v2 + 1e-9f;
            top_out[(size_t)token * 2 + 0] = v1 / dnm;
            top_out[(size_t)token * 2 + 1] = v2 / dnm;
            idx_out[(size_t)token * 2 + 0] = (float)i1;
            idx_out[(size_t)token * 2 + 1] = (float)i2;
        }
    }
}

// ---- fallback (no workspace): validated structure, W read natural layout ----
#define BK  128
#define BKP (BK + 4)
__device__ __forceinline__ float rl(float v, int l) {
    return __int_as_float(__builtin_amdgcn_readlane(__float_as_int(v), l));
}
__global__ __launch_bounds__(128) void router_fallback(
    const float* __restrict__ x, const float* __restrict__ W,
    const float* __restrict__ b, float* __restrict__ out)
{
    __shared__ float wt[NEXP * BKP];
    const int tid  = threadIdx.x;
    const int lane = tid & 63;
    const int wv   = __builtin_amdgcn_readfirstlane(tid >> 6);
    const int tok0 = blockIdx.x * 16 + wv * 8;
    const float* __restrict__ xw = x + (size_t)tok0 * D_MODEL;

    float2 xcur[8], xnxt[8];
#pragma unroll
    for (int t = 0; t < 8; t++)
        xcur[t] = *(const float2*)(xw + (size_t)t * D_MODEL + 2 * lane);
    float accm[8];
#pragma unroll
    for (int t = 0; t < 8; t++) accm[t] = 0.f;

    for (int c = 0; c < D_MODEL / BK; c++) {
        const int k0 = c * BK;
        if (c + 1 < D_MODEL / BK) {
#pragma unroll
            for (int t = 0; t < 8; t++)
                xnxt[t] = *(const float2*)(xw + (size_t)t * D_MODEL + (k0 + BK) + 2 * lane);
        }
#pragma unroll
        for (int i = 0; i < 16; i++) {
            int n  = i * 128 + tid;
            int dd = n >> 4;
            int e0 = (n & 15) * 4;
            float4 v = *(const float4*)(W + (size_t)(k0 + dd) * NEXP + e0);
            wt[(e0 + 0) * BKP + dd] = v.x;
            wt[(e0 + 1) * BKP + dd] = v.y;
            wt[(e0 + 2) * BKP + dd] = v.z;
            wt[(e0 + 3) * BKP + dd] = v.w;
        }
        __syncthreads();
        float acc[8];
#pragma unroll
        for (int t = 0; t < 8; t++) acc[t] = 0.f;
        const float* wl = &wt[lane * BKP];
#pragma unroll 4
        for (int kk = 0; kk < BK; kk += 4) {
            float4 w4 = *(const float4*)(wl + kk);
            const int l0 = kk >> 1;
#pragma unroll
            for (int t = 0; t < 8; t++) {
                float a = acc[t];
                a = fmaf(rl(xcur[t].x, l0    ), w4.x, a);
                a = fmaf(rl(xcur[t].y, l0    ), w4.y, a);
                a = fmaf(rl(xcur[t].x, l0 + 1), w4.z, a);
                a = fmaf(rl(xcur[t].y, l0 + 1), w4.w, a);
                acc[t] = a;
            }
        }
#pragma unroll
        for (int t = 0; t < 8; t++) accm[t] += acc[t];
        __syncthreads();
#pragma unroll
        for (int t = 0; t < 8; t++) xcur[t] = xnxt[t];
    }

    const float bias = b[lane];
    float* __restrict__ probs_out = out;
    float* __restrict__ top_out   = out + (size_t)NTOK * NEXP;
    float* __restrict__ idx_out   = top_out + (size_t)NTOK * 2;
#pragma unroll 1
    for (int t = 0; t < 8; t++) {
        const int token = tok0 + t;
        float logit = accm[t] + bias;
        float mx = logit;
#pragma unroll
        for (int off = 32; off; off >>= 1) mx = fmaxf(mx, __shfl_xor(mx, off, 64));
        float ex = expf(logit - mx);
        float s = ex;
#pragma unroll
        for (int off = 32; off; off >>= 1) s += __shfl_xor(s, off, 64);
        float p = ex / s;
        probs_out[(size_t)token * NEXP + lane] = p;
        float v = p; int idx = lane;
#pragma unroll
        for (int off = 32; off; off >>= 1) {
            float ov = __shfl_xor(v, off, 64);
            int   oi = __shfl_xor(idx, off, 64);
            if (ov > v || (ov == v && oi < idx)) { v = ov; idx = oi; }
        }
        const float v1 = v; const int i1 = idx;
        v = (lane == i1) ? -1.0f : p; idx = lane;
#pragma unroll
        for (int off = 32; off; off >>= 1) {
            float ov = __shfl_xor(v, off, 64);
            int   oi = __shfl_xor(idx, off, 64);
            if (ov > v || (ov == v && oi < idx)) { v = ov; idx = oi; }
        }
        const float v2 = v; const int i2 = idx;
        if (lane == 0) {
            const float dnm = v1 + v2 + 1e-9f;
            top_out[(size_t)token * 2 + 0] = v1 / dnm;
            top_out[(size_t)token * 2 + 1] = v2 / dnm;
            idx_out[(size_t)token * 2 + 0] = (float)i1;
            idx_out[(size_t)token * 2 + 1] = (float)i2;
        }
    }
}

extern "C" void kernel_launch(void* const* d_in, const int* in_sizes, int n_in,
                              void* d_out, int out_size, void* d_ws, size_t ws_size,
                              hipStream_t stream) {
    const float* x = (const float*)d_in[0];
    const float* W = (const float*)d_in[1];
    const float* b = (const float*)d_in[2];
    float* out = (float*)d_out;

    const size_t need = (size_t)NKS * 4 * 2 * 64 * 16;   // 1 MiB of f16 fragments
    if (ws_size >= need) {
        prep_w<<<128, 256, 0, stream>>>(W, (half8*)d_ws);
        router_mfma<<<NTOK / 32, 256, 0, stream>>>(x, (const int4*)d_ws, b, out);
    } else {
        router_fallback<<<NTOK / 16, 128, 0, stream>>>(x, W, b, out);
    }
}

// Round 6
// 372.754 us; speedup vs baseline: 1.1214x; 1.0335x over previous
//
#include <hip/hip_runtime.h>

#define D_MODEL 4096
#define NEXP    64
#define NTOK    16384
#define NKS     128              // k-steps of 32: 4096/32

typedef _Float16 half8 __attribute__((ext_vector_type(8)));
typedef float    f32x4 __attribute__((ext_vector_type(4)));

// Dekker-style split of 8 fp32 into f16 hi + f16 lo planes (RTZ; lo catches residual)
__device__ __forceinline__ void split8(float4 a, float4 b, half8& hi, half8& lo) {
    auto h0 = __builtin_amdgcn_cvt_pkrtz(a.x, a.y);
    auto h1 = __builtin_amdgcn_cvt_pkrtz(a.z, a.w);
    auto h2 = __builtin_amdgcn_cvt_pkrtz(b.x, b.y);
    auto h3 = __builtin_amdgcn_cvt_pkrtz(b.z, b.w);
    hi[0] = static_cast<_Float16>(h0[0]); hi[1] = static_cast<_Float16>(h0[1]);
    hi[2] = static_cast<_Float16>(h1[0]); hi[3] = static_cast<_Float16>(h1[1]);
    hi[4] = static_cast<_Float16>(h2[0]); hi[5] = static_cast<_Float16>(h2[1]);
    hi[6] = static_cast<_Float16>(h3[0]); hi[7] = static_cast<_Float16>(h3[1]);
    float r0 = a.x - (float)h0[0], r1 = a.y - (float)h0[1];
    float r2 = a.z - (float)h1[0], r3 = a.w - (float)h1[1];
    float r4 = b.x - (float)h2[0], r5 = b.y - (float)h2[1];
    float r6 = b.z - (float)h3[0], r7 = b.w - (float)h3[1];
    auto l0 = __builtin_amdgcn_cvt_pkrtz(r0, r1);
    auto l1 = __builtin_amdgcn_cvt_pkrtz(r2, r3);
    auto l2 = __builtin_amdgcn_cvt_pkrtz(r4, r5);
    auto l3 = __builtin_amdgcn_cvt_pkrtz(r6, r7);
    lo[0] = static_cast<_Float16>(l0[0]); lo[1] = static_cast<_Float16>(l0[1]);
    lo[2] = static_cast<_Float16>(l1[0]); lo[3] = static_cast<_Float16>(l1[1]);
    lo[4] = static_cast<_Float16>(l2[0]); lo[5] = static_cast<_Float16>(l2[1]);
    lo[6] = static_cast<_Float16>(l3[0]); lo[7] = static_cast<_Float16>(l3[1]);
}

// async global->LDS DMA, 16 B/lane: per-lane global src, wave-uniform LDS base;
// HW writes lane l at base + l*16 (mechanism verified by R2-R5 passing).
__device__ __forceinline__ void dma16(const float* g, float* l) {
    __builtin_amdgcn_global_load_lds(
        (const __attribute__((address_space(1))) unsigned int*)g,
        (__attribute__((address_space(3))) unsigned int*)l,
        16, 0, 0);
}

// ---- W prep: split fp32 W[d][e] into f16 hi/lo planes, laid out in exact
// B-fragment order: frag fi = ((ks*4 + tile)*2 + plane), 64 lanes x 16B each.
// Lane l of frag: expert = 16*tile + (l&15), k = ks*32 + (l>>4)*8 + j, j=0..7.
__global__ __launch_bounds__(256) void prep_w(const float* __restrict__ W,
                                              half8* __restrict__ ws) {
    const int gid  = blockIdx.x * 256 + threadIdx.x;   // 0..32767
    const int lane = gid & 63;
    const int fp   = gid >> 6;                         // 0..511 = ks*4 + tile
    const int t    = fp & 3;
    const int ks   = fp >> 2;
    const int e    = 16 * t + (lane & 15);
    const int k0   = ks * 32 + (lane >> 4) * 8;
    float4 a, b;
    a.x = W[(size_t)(k0 + 0) * NEXP + e];
    a.y = W[(size_t)(k0 + 1) * NEXP + e];
    a.z = W[(size_t)(k0 + 2) * NEXP + e];
    a.w = W[(size_t)(k0 + 3) * NEXP + e];
    b.x = W[(size_t)(k0 + 4) * NEXP + e];
    b.y = W[(size_t)(k0 + 5) * NEXP + e];
    b.z = W[(size_t)(k0 + 6) * NEXP + e];
    b.w = W[(size_t)(k0 + 7) * NEXP + e];
    half8 hi, lo;
    split8(a, b, hi, lo);
    ws[(size_t)(fp * 2 + 0) * 64 + lane] = hi;
    ws[(size_t)(fp * 2 + 1) * 64 + lane] = lo;
}

// ---- main: block = 16 tokens, 4 waves split EXPERTS (16 each), full K per wave.
// x staged cooperatively: window = [16 rows][256 floats] (8 k-steps), one DMA
// per row = 1024 B CONTIGUOUS burst (DRAM page locality — the fix). Double
// buffered, counted vmcnt(4) + raw s_barrier pair per window (m201 pattern).
// Row stride 260 floats: transposed ds_reads spread 8 lanes/bank-quad (uniform).
__global__ __launch_bounds__(256, 4) void router_mfma(
    const float* __restrict__ x, const int4* __restrict__ wf,
    const float* __restrict__ b, float* __restrict__ out)
{
    __shared__ float xs[2][16][260];                   // 33280 B
    const int tid  = threadIdx.x;
    const int lane = tid & 63;
    const int wv   = tid >> 6;                         // expert-tile index 0..3
    const int tok0 = blockIdx.x * 16;
    const int m    = lane & 15;
    const int q    = lane >> 4;

    // staging: wave wv owns rows wv*4..wv*4+3; per-lane src = row + lane*16B
    const float* xsrc[4];
#pragma unroll
    for (int d = 0; d < 4; d++)
        xsrc[d] = x + (size_t)(tok0 + wv * 4 + d) * D_MODEL + lane * 4;
    const int4* __restrict__ wq = wf + lane;

    f32x4 acc = {};                                    // 16 tok x 16 exp tile
    int4  wA[2], wB[2];                                // W hi/lo, 2-deep

    auto stage = [&](int w, int buf) {
#pragma unroll
        for (int d = 0; d < 4; d++)
            dma16(xsrc[d] + w * 256, &xs[buf][wv * 4 + d][0]);
    };
    auto ldw = [&](int4 (&W)[2], int ks) {
        const int base = ks * 512 + wv * 128;          // fi=(ks*4+wv)*2, *64 int4
        W[0] = wq[base];
        W[1] = wq[base + 64];
    };
    auto cmp = [&](int buf, int s, int4 (&Wb)[2]) {
        const float* px = &xs[buf][m][s * 32 + q * 8];
        float4 xa = *(const float4*)px;
        float4 xb = *(const float4*)(px + 4);
        half8 ahi, alo;
        split8(xa, xb, ahi, alo);
        half8 bhi = __builtin_bit_cast(half8, Wb[0]);
        half8 blo = __builtin_bit_cast(half8, Wb[1]);
        acc = __builtin_amdgcn_mfma_f32_16x16x32_f16(ahi, bhi, acc, 0, 0, 0);
        acc = __builtin_amdgcn_mfma_f32_16x16x32_f16(ahi, blo, acc, 0, 0, 0);
        acc = __builtin_amdgcn_mfma_f32_16x16x32_f16(alo, bhi, acc, 0, 0, 0);
    };

    // prologue: window 0 + first W
    ldw(wA, 0);
    stage(0, 0);

#pragma unroll 1
    for (int w = 0; w < 16; w++) {                     // 16 windows x 8 k-steps
        const int buf = w & 1;
        if (w < 15) {
            stage(w + 1, buf ^ 1);
            // 4 newest outstanding = next window's DMAs; this window's DMAs
            // (older) are done. W reg-loads have their own compiler waits.
            asm volatile("s_waitcnt vmcnt(4)" ::: "memory");
        } else {
            asm volatile("s_waitcnt vmcnt(0)" ::: "memory");
        }
        __builtin_amdgcn_sched_barrier(0);
        __builtin_amdgcn_s_barrier();                  // A: window-w visible to all
        __builtin_amdgcn_sched_barrier(0);
        const int ks0 = w * 8;
#pragma unroll
        for (int s = 0; s < 8; s += 2) {
            ldw(wB, ks0 + s + 1);
            cmp(buf, s, wA);
            const int nk = (s == 6) ? ((w < 15) ? ks0 + 8 : 0) : ks0 + s + 2;
            ldw(wA, nk);
            cmp(buf, s + 1, wB);
        }
        __builtin_amdgcn_sched_barrier(0);
        __builtin_amdgcn_s_barrier();                  // B: all reads of buf done
        __builtin_amdgcn_sched_barrier(0);
    }

    // C/D layout (verified m89/m91): col = lane&15 (expert-in-tile), row = q*4+r.
    // Exchange partials via (now dead) staging LDS: part[16 tokens][68].
    float* part = &xs[0][0][0];
#pragma unroll
    for (int r = 0; r < 4; r++)
        part[(q * 4 + r) * 68 + wv * 16 + m] = acc[r];
    __syncthreads();

    const float bias = b[lane];
    float* __restrict__ probs_out = out;
    float* __restrict__ top_out   = out + (size_t)NTOK * NEXP;
    float* __restrict__ idx_out   = top_out + (size_t)NTOK * 2;

    // each wave finishes 4 token rows: softmax + top-2 over 64 experts
#pragma unroll 1
    for (int r2 = 0; r2 < 4; r2++) {
        const int row   = wv * 4 + r2;
        const int token = tok0 + row;
        float logit = part[row * 68 + lane] + bias;

        float mx = logit;
#pragma unroll
        for (int off = 32; off; off >>= 1) mx = fmaxf(mx, __shfl_xor(mx, off, 64));
        float ex = expf(logit - mx);
        float s = ex;
#pragma unroll
        for (int off = 32; off; off >>= 1) s += __shfl_xor(s, off, 64);
        float p = ex / s;
        probs_out[(size_t)token * NEXP + lane] = p;

        // top-1 (lowest index wins ties, matching lax.top_k)
        float v = p; int idx = lane;
#pragma unroll
        for (int off = 32; off; off >>= 1) {
            float ov = __shfl_xor(v, off, 64);
            int   oi = __shfl_xor(idx, off, 64);
            if (ov > v || (ov == v && oi < idx)) { v = ov; idx = oi; }
        }
        const float v1 = v; const int i1 = idx;
        // top-2
        v = (lane == i1) ? -1.0f : p; idx = lane;
#pragma unroll
        for (int off = 32; off; off >>= 1) {
            float ov = __shfl_xor(v, off, 64);
            int   oi = __shfl_xor(idx, off, 64);
            if (ov > v || (ov == v && oi < idx)) { v = ov; idx = oi; }
        }
        const float v2 = v; const int i2 = idx;

        if (lane == 0) {
            const float dnm = v1 + v2 + 1e-9f;
            top_out[(size_t)token * 2 + 0] = v1 / dnm;
            top_out[(size_t)token * 2 + 1] = v2 / dnm;
            idx_out[(size_t)token * 2 + 0] = (float)i1;
            idx_out[(size_t)token * 2 + 1] = (float)i2;
        }
    }
}

// ---- fallback (no workspace): validated structure, W read natural layout ----
#define BK  128
#define BKP (BK + 4)
__device__ __forceinline__ float rl(float v, int l) {
    return __int_as_float(__builtin_amdgcn_readlane(__float_as_int(v), l));
}
__global__ __launch_bounds__(128) void router_fallback(
    const float* __restrict__ x, const float* __restrict__ W,
    const float* __restrict__ b, float* __restrict__ out)
{
    __shared__ float wt[NEXP * BKP];
    const int tid  = threadIdx.x;
    const int lane = tid & 63;
    const int wv   = __builtin_amdgcn_readfirstlane(tid >> 6);
    const int tok0 = blockIdx.x * 16 + wv * 8;
    const float* __restrict__ xw = x + (size_t)tok0 * D_MODEL;

    float2 xcur[8], xnxt[8];
#pragma unroll
    for (int t = 0; t < 8; t++)
        xcur[t] = *(const float2*)(xw + (size_t)t * D_MODEL + 2 * lane);
    float accm[8];
#pragma unroll
    for (int t = 0; t < 8; t++) accm[t] = 0.f;

    for (int c = 0; c < D_MODEL / BK; c++) {
        const int k0 = c * BK;
        if (c + 1 < D_MODEL / BK) {
#pragma unroll
            for (int t = 0; t < 8; t++)
                xnxt[t] = *(const float2*)(xw + (size_t)t * D_MODEL + (k0 + BK) + 2 * lane);
        }
#pragma unroll
        for (int i = 0; i < 16; i++) {
            int n  = i * 128 + tid;
            int dd = n >> 4;
            int e0 = (n & 15) * 4;
            float4 v = *(const float4*)(W + (size_t)(k0 + dd) * NEXP + e0);
            wt[(e0 + 0) * BKP + dd] = v.x;
            wt[(e0 + 1) * BKP + dd] = v.y;
            wt[(e0 + 2) * BKP + dd] = v.z;
            wt[(e0 + 3) * BKP + dd] = v.w;
        }
        __syncthreads();
        float acc[8];
#pragma unroll
        for (int t = 0; t < 8; t++) acc[t] = 0.f;
        const float* wl = &wt[lane * BKP];
#pragma unroll 4
        for (int kk = 0; kk < BK; kk += 4) {
            float4 w4 = *(const float4*)(wl + kk);
            const int l0 = kk >> 1;
#pragma unroll
            for (int t = 0; t < 8; t++) {
                float a = acc[t];
                a = fmaf(rl(xcur[t].x, l0    ), w4.x, a);
                a = fmaf(rl(xcur[t].y, l0    ), w4.y, a);
                a = fmaf(rl(xcur[t].x, l0 + 1), w4.z, a);
                a = fmaf(rl(xcur[t].y, l0 + 1), w4.w, a);
                acc[t] = a;
            }
        }
#pragma unroll
        for (int t = 0; t < 8; t++) accm[t] += acc[t];
        __syncthreads();
#pragma unroll
        for (int t = 0; t < 8; t++) xcur[t] = xnxt[t];
    }

    const float bias = b[lane];
    float* __restrict__ probs_out = out;
    float* __restrict__ top_out   = out + (size_t)NTOK * NEXP;
    float* __restrict__ idx_out   = top_out + (size_t)NTOK * 2;
#pragma unroll 1
    for (int t = 0; t < 8; t++) {
        const int token = tok0 + t;
        float logit = accm[t] + bias;
        float mx = logit;
#pragma unroll
        for (int off = 32; off; off >>= 1) mx = fmaxf(mx, __shfl_xor(mx, off, 64));
        float ex = expf(logit - mx);
        float s = ex;
#pragma unroll
        for (int off = 32; off; off >>= 1) s += __shfl_xor(s, off, 64);
        float p = ex / s;
        probs_out[(size_t)token * NEXP + lane] = p;
        float v = p; int idx = lane;
#pragma unroll
        for (int off = 32; off; off >>= 1) {
            float ov = __shfl_xor(v, off, 64);
            int   oi = __shfl_xor(idx, off, 64);
            if (ov > v || (ov == v && oi < idx)) { v = ov; idx = oi; }
        }
        const float v1 = v; const int i1 = idx;
        v = (lane == i1) ? -1.0f : p; idx = lane;
#pragma unroll
        for (int off = 32; off; off >>= 1) {
            float ov = __shfl_xor(v, off, 64);
            int   oi = __shfl_xor(idx, off, 64);
            if (ov > v || (ov == v && oi < idx)) { v = ov; idx = oi; }
        }
        const float v2 = v; const int i2 = idx;
        if (lane == 0) {
            const float dnm = v1 + v2 + 1e-9f;
            top_out[(size_t)token * 2 + 0] = v1 / dnm;
            top_out[(size_t)token * 2 + 1] = v2 / dnm;
            idx_out[(size_t)token * 2 + 0] = (float)i1;
            idx_out[(size_t)token * 2 + 1] = (float)i2;
        }
    }
}

extern "C" void kernel_launch(void* const* d_in, const int* in_sizes, int n_in,
                              void* d_out, int out_size, void* d_ws, size_t ws_size,
                              hipStream_t stream) {
    const float* x = (const float*)d_in[0];
    const float* W = (const float*)d_in[1];
    const float* b = (const float*)d_in[2];
    float* out = (float*)d_out;

    const size_t need = (size_t)NKS * 4 * 2 * 64 * 16;   // 1 MiB of f16 fragments
    if (ws_size >= need) {
        prep_w<<<128, 256, 0, stream>>>(W, (half8*)d_ws);
        router_mfma<<<NTOK / 16, 256, 0, stream>>>(x, (const int4*)d_ws, b, out);
    } else {
        router_fallback<<<NTOK / 16, 128, 0, stream>>>(x, W, b, out);
    }
}

// Round 7
// 371.819 us; speedup vs baseline: 1.1243x; 1.0025x over previous
//
#include <hip/hip_runtime.h>

#define D_MODEL 4096
#define NEXP    64
#define NTOK    16384
#define NKS     128              // k-steps of 32: 4096/32

typedef _Float16 half8 __attribute__((ext_vector_type(8)));
typedef float    f32x4 __attribute__((ext_vector_type(4)));

// Dekker-style split of 8 fp32 into f16 hi + f16 lo planes (RTZ; lo catches residual)
__device__ __forceinline__ void split8(float4 a, float4 b, half8& hi, half8& lo) {
    auto h0 = __builtin_amdgcn_cvt_pkrtz(a.x, a.y);
    auto h1 = __builtin_amdgcn_cvt_pkrtz(a.z, a.w);
    auto h2 = __builtin_amdgcn_cvt_pkrtz(b.x, b.y);
    auto h3 = __builtin_amdgcn_cvt_pkrtz(b.z, b.w);
    hi[0] = static_cast<_Float16>(h0[0]); hi[1] = static_cast<_Float16>(h0[1]);
    hi[2] = static_cast<_Float16>(h1[0]); hi[3] = static_cast<_Float16>(h1[1]);
    hi[4] = static_cast<_Float16>(h2[0]); hi[5] = static_cast<_Float16>(h2[1]);
    hi[6] = static_cast<_Float16>(h3[0]); hi[7] = static_cast<_Float16>(h3[1]);
    float r0 = a.x - (float)h0[0], r1 = a.y - (float)h0[1];
    float r2 = a.z - (float)h1[0], r3 = a.w - (float)h1[1];
    float r4 = b.x - (float)h2[0], r5 = b.y - (float)h2[1];
    float r6 = b.z - (float)h3[0], r7 = b.w - (float)h3[1];
    auto l0 = __builtin_amdgcn_cvt_pkrtz(r0, r1);
    auto l1 = __builtin_amdgcn_cvt_pkrtz(r2, r3);
    auto l2 = __builtin_amdgcn_cvt_pkrtz(r4, r5);
    auto l3 = __builtin_amdgcn_cvt_pkrtz(r6, r7);
    lo[0] = static_cast<_Float16>(l0[0]); lo[1] = static_cast<_Float16>(l0[1]);
    lo[2] = static_cast<_Float16>(l1[0]); lo[3] = static_cast<_Float16>(l1[1]);
    lo[4] = static_cast<_Float16>(l2[0]); lo[5] = static_cast<_Float16>(l2[1]);
    lo[6] = static_cast<_Float16>(l3[0]); lo[7] = static_cast<_Float16>(l3[1]);
}

// async global->LDS DMA, 16 B/lane: per-lane global src, wave-uniform LDS base;
// HW writes lane l at base + l*16 (mechanism verified R2-R6 passing).
__device__ __forceinline__ void dma16(const float* g, float* l) {
    __builtin_amdgcn_global_load_lds(
        (const __attribute__((address_space(1))) unsigned int*)g,
        (__attribute__((address_space(3))) unsigned int*)l,
        16, 0, 0);
}

// ---- W prep: split fp32 W[d][e] into f16 hi/lo planes, laid out in exact
// B-fragment order: frag fi = ((ks*4 + tile)*2 + plane), 64 lanes x 16B each.
// Lane l of frag: expert = 16*tile + (l&15), k = ks*32 + (l>>4)*8 + j, j=0..7.
__global__ __launch_bounds__(256) void prep_w(const float* __restrict__ W,
                                              half8* __restrict__ ws) {
    const int gid  = blockIdx.x * 256 + threadIdx.x;   // 0..32767
    const int lane = gid & 63;
    const int fp   = gid >> 6;                         // 0..511 = ks*4 + tile
    const int t    = fp & 3;
    const int ks   = fp >> 2;
    const int e    = 16 * t + (lane & 15);
    const int k0   = ks * 32 + (lane >> 4) * 8;
    float4 a, b;
    a.x = W[(size_t)(k0 + 0) * NEXP + e];
    a.y = W[(size_t)(k0 + 1) * NEXP + e];
    a.z = W[(size_t)(k0 + 2) * NEXP + e];
    a.w = W[(size_t)(k0 + 3) * NEXP + e];
    b.x = W[(size_t)(k0 + 4) * NEXP + e];
    b.y = W[(size_t)(k0 + 5) * NEXP + e];
    b.z = W[(size_t)(k0 + 6) * NEXP + e];
    b.w = W[(size_t)(k0 + 7) * NEXP + e];
    half8 hi, lo;
    split8(a, b, hi, lo);
    ws[(size_t)(fp * 2 + 0) * 64 + lane] = hi;
    ws[(size_t)(fp * 2 + 1) * 64 + lane] = lo;
}

// ---- main: block = 16 tokens, 4 waves split EXPERTS (16 each), full K.
// Single barrier per window (16 total). stage(w+1) issued right after the
// barrier -> 16 KB in flight under the whole window's compute. W prefetched
// in a distance-4 register ring (>= L2 latency). Trailing vmcnt(4) exploits
// in-order VMEM retirement (m135): suffix-4 = last 2 ring loads, so the
// window's stage DMAs are guaranteed drained before the barrier.
__global__ __launch_bounds__(256, 4) void router_mfma(
    const float* __restrict__ x, const int4* __restrict__ wf,
    const float* __restrict__ b, float* __restrict__ out)
{
    __shared__ float xs[2][16][260];                   // 33280 B, +4 pad/row
    const int tid  = threadIdx.x;
    const int lane = tid & 63;
    const int wv   = tid >> 6;                         // expert-tile index 0..3
    const int tok0 = blockIdx.x * 16;
    const int m    = lane & 15;
    const int q    = lane >> 4;

    // staging: wave wv owns rows wv*4..wv*4+3; per-lane src = row + lane*16B
    const float* xsrc[4];
#pragma unroll
    for (int d = 0; d < 4; d++)
        xsrc[d] = x + (size_t)(tok0 + wv * 4 + d) * D_MODEL + lane * 4;
    const int4* __restrict__ wq = wf + lane;

    f32x4 acc = {};                                    // 16 tok x 16 exp tile
    int4  ring[4][2];                                  // W hi/lo, distance-4 ring

    auto stage = [&](int w, int buf) {
#pragma unroll
        for (int d = 0; d < 4; d++)
            dma16(xsrc[d] + w * 256, &xs[buf][wv * 4 + d][0]);
    };
    auto ldw = [&](int slot, int ks) {
        const int base = ks * 512 + wv * 128;          // fi=(ks*4+wv)*2, *64 int4
        ring[slot][0] = wq[base];
        ring[slot][1] = wq[base + 64];
    };
    auto cmp = [&](int buf, int s, int slot) {
        const float* px = &xs[buf][m][s * 32 + q * 8];
        float4 xa = *(const float4*)px;                // ds_read_b128 pair
        float4 xb = *(const float4*)(px + 4);
        half8 ahi, alo;
        split8(xa, xb, ahi, alo);
        half8 bhi = __builtin_bit_cast(half8, ring[slot][0]);
        half8 blo = __builtin_bit_cast(half8, ring[slot][1]);
        acc = __builtin_amdgcn_mfma_f32_16x16x32_f16(ahi, bhi, acc, 0, 0, 0);
        acc = __builtin_amdgcn_mfma_f32_16x16x32_f16(ahi, blo, acc, 0, 0, 0);
        acc = __builtin_amdgcn_mfma_f32_16x16x32_f16(alo, bhi, acc, 0, 0, 0);
    };

    // prologue: window 0 + W ring k=0..3; drain win0 (suffix-8 = ring loads)
    stage(0, 0);
#pragma unroll
    for (int s = 0; s < 4; s++) ldw(s, s);
    asm volatile("s_waitcnt vmcnt(8)" ::: "memory");   // win0 landed (in-order)
    __builtin_amdgcn_sched_barrier(0);
    __builtin_amdgcn_s_barrier();
    __builtin_amdgcn_sched_barrier(0);

#pragma unroll 1
    for (int w = 0; w < 16; w++) {                     // 16 windows x 8 k-steps
        const int buf = w & 1;
        if (w < 15) stage(w + 1, buf ^ 1);             // in flight all window
        __builtin_amdgcn_sched_barrier(0);
        const int ks0 = w * 8;
#pragma unroll
        for (int s = 0; s < 8; s++) {
            cmp(buf, s, s & 3);
            ldw(s & 3, (ks0 + s + 4) & 127);           // distance-4; wrap safe
        }
        __builtin_amdgcn_sched_barrier(0);
        if (w < 15)
            // suffix-4 = last 2 ring ldw; everything older (stage w+1) done
            asm volatile("s_waitcnt vmcnt(4)" ::: "memory");
        else
            asm volatile("s_waitcnt vmcnt(0)" ::: "memory");
        __builtin_amdgcn_sched_barrier(0);
        __builtin_amdgcn_s_barrier();                  // window w+1 visible
        __builtin_amdgcn_sched_barrier(0);
    }

    // C/D layout (verified m89/m91): col = lane&15 (expert-in-tile), row = q*4+r.
    // Exchange logits via (now dead) staging LDS: part[16 tokens][68].
    float* part = &xs[0][0][0];
#pragma unroll
    for (int r = 0; r < 4; r++)
        part[(q * 4 + r) * 68 + wv * 16 + m] = acc[r];
    __syncthreads();

    const float bias = b[lane];
    float* __restrict__ probs_out = out;
    float* __restrict__ top_out   = out + (size_t)NTOK * NEXP;
    float* __restrict__ idx_out   = top_out + (size_t)NTOK * 2;

    // each wave finishes 4 token rows: softmax + top-2 over 64 experts
#pragma unroll 1
    for (int r2 = 0; r2 < 4; r2++) {
        const int row   = wv * 4 + r2;
        const int token = tok0 + row;
        float logit = part[row * 68 + lane] + bias;

        float mx = logit;
#pragma unroll
        for (int off = 32; off; off >>= 1) mx = fmaxf(mx, __shfl_xor(mx, off, 64));
        float ex = expf(logit - mx);
        float s = ex;
#pragma unroll
        for (int off = 32; off; off >>= 1) s += __shfl_xor(s, off, 64);
        float p = ex / s;
        probs_out[(size_t)token * NEXP + lane] = p;

        // top-1 (lowest index wins ties, matching lax.top_k)
        float v = p; int idx = lane;
#pragma unroll
        for (int off = 32; off; off >>= 1) {
            float ov = __shfl_xor(v, off, 64);
            int   oi = __shfl_xor(idx, off, 64);
            if (ov > v || (ov == v && oi < idx)) { v = ov; idx = oi; }
        }
        const float v1 = v; const int i1 = idx;
        // top-2
        v = (lane == i1) ? -1.0f : p; idx = lane;
#pragma unroll
        for (int off = 32; off; off >>= 1) {
            float ov = __shfl_xor(v, off, 64);
            int   oi = __shfl_xor(idx, off, 64);
            if (ov > v || (ov == v && oi < idx)) { v = ov; idx = oi; }
        }
        const float v2 = v; const int i2 = idx;

        if (lane == 0) {
            const float dnm = v1 + v2 + 1e-9f;
            top_out[(size_t)token * 2 + 0] = v1 / dnm;
            top_out[(size_t)token * 2 + 1] = v2 / dnm;
            idx_out[(size_t)token * 2 + 0] = (float)i1;
            idx_out[(size_t)token * 2 + 1] = (float)i2;
        }
    }
}

// ---- fallback (no workspace): validated structure, W read natural layout ----
#define BK  128
#define BKP (BK + 4)
__device__ __forceinline__ float rl(float v, int l) {
    return __int_as_float(__builtin_amdgcn_readlane(__float_as_int(v), l));
}
__global__ __launch_bounds__(128) void router_fallback(
    const float* __restrict__ x, const float* __restrict__ W,
    const float* __restrict__ b, float* __restrict__ out)
{
    __shared__ float wt[NEXP * BKP];
    const int tid  = threadIdx.x;
    const int lane = tid & 63;
    const int wv   = __builtin_amdgcn_readfirstlane(tid >> 6);
    const int tok0 = blockIdx.x * 16 + wv * 8;
    const float* __restrict__ xw = x + (size_t)tok0 * D_MODEL;

    float2 xcur[8], xnxt[8];
#pragma unroll
    for (int t = 0; t < 8; t++)
        xcur[t] = *(const float2*)(xw + (size_t)t * D_MODEL + 2 * lane);
    float accm[8];
#pragma unroll
    for (int t = 0; t < 8; t++) accm[t] = 0.f;

    for (int c = 0; c < D_MODEL / BK; c++) {
        const int k0 = c * BK;
        if (c + 1 < D_MODEL / BK) {
#pragma unroll
            for (int t = 0; t < 8; t++)
                xnxt[t] = *(const float2*)(xw + (size_t)t * D_MODEL + (k0 + BK) + 2 * lane);
        }
#pragma unroll
        for (int i = 0; i < 16; i++) {
            int n  = i * 128 + tid;
            int dd = n >> 4;
            int e0 = (n & 15) * 4;
            float4 v = *(const float4*)(W + (size_t)(k0 + dd) * NEXP + e0);
            wt[(e0 + 0) * BKP + dd] = v.x;
            wt[(e0 + 1) * BKP + dd] = v.y;
            wt[(e0 + 2) * BKP + dd] = v.z;
            wt[(e0 + 3) * BKP + dd] = v.w;
        }
        __syncthreads();
        float acc[8];
#pragma unroll
        for (int t = 0; t < 8; t++) acc[t] = 0.f;
        const float* wl = &wt[lane * BKP];
#pragma unroll 4
        for (int kk = 0; kk < BK; kk += 4) {
            float4 w4 = *(const float4*)(wl + kk);
            const int l0 = kk >> 1;
#pragma unroll
            for (int t = 0; t < 8; t++) {
                float a = acc[t];
                a = fmaf(rl(xcur[t].x, l0    ), w4.x, a);
                a = fmaf(rl(xcur[t].y, l0    ), w4.y, a);
                a = fmaf(rl(xcur[t].x, l0 + 1), w4.z, a);
                a = fmaf(rl(xcur[t].y, l0 + 1), w4.w, a);
                acc[t] = a;
            }
        }
#pragma unroll
        for (int t = 0; t < 8; t++) accm[t] += acc[t];
        __syncthreads();
#pragma unroll
        for (int t = 0; t < 8; t++) xcur[t] = xnxt[t];
    }

    const float bias = b[lane];
    float* __restrict__ probs_out = out;
    float* __restrict__ top_out   = out + (size_t)NTOK * NEXP;
    float* __restrict__ idx_out   = top_out + (size_t)NTOK * 2;
#pragma unroll 1
    for (int t = 0; t < 8; t++) {
        const int token = tok0 + t;
        float logit = accm[t] + bias;
        float mx = logit;
#pragma unroll
        for (int off = 32; off; off >>= 1) mx = fmaxf(mx, __shfl_xor(mx, off, 64));
        float ex = expf(logit - mx);
        float s = ex;
#pragma unroll
        for (int off = 32; off; off >>= 1) s += __shfl_xor(s, off, 64);
        float p = ex / s;
        probs_out[(size_t)token * NEXP + lane] = p;
        float v = p; int idx = lane;
#pragma unroll
        for (int off = 32; off; off >>= 1) {
            float ov = __shfl_xor(v, off, 64);
            int   oi = __shfl_xor(idx, off, 64);
            if (ov > v || (ov == v && oi < idx)) { v = ov; idx = oi; }
        }
        const float v1 = v; const int i1 = idx;
        v = (lane == i1) ? -1.0f : p; idx = lane;
#pragma unroll
        for (int off = 32; off; off >>= 1) {
            float ov = __shfl_xor(v, off, 64);
            int   oi = __shfl_xor(idx, off, 64);
            if (ov > v || (ov == v && oi < idx)) { v = ov; idx = oi; }
        }
        const float v2 = v; const int i2 = idx;
        if (lane == 0) {
            const float dnm = v1 + v2 + 1e-9f;
            top_out[(size_t)token * 2 + 0] = v1 / dnm;
            top_out[(size_t)token * 2 + 1] = v2 / dnm;
            idx_out[(size_t)token * 2 + 0] = (float)i1;
            idx_out[(size_t)token * 2 + 1] = (float)i2;
        }
    }
}

extern "C" void kernel_launch(void* const* d_in, const int* in_sizes, int n_in,
                              void* d_out, int out_size, void* d_ws, size_t ws_size,
                              hipStream_t stream) {
    const float* x = (const float*)d_in[0];
    const float* W = (const float*)d_in[1];
    const float* b = (const float*)d_in[2];
    float* out = (float*)d_out;

    const size_t need = (size_t)NKS * 4 * 2 * 64 * 16;   // 1 MiB of f16 fragments
    if (ws_size >= need) {
        prep_w<<<128, 256, 0, stream>>>(W, (half8*)d_ws);
        router_mfma<<<NTOK / 16, 256, 0, stream>>>(x, (const int4*)d_ws, b, out);
    } else {
        router_fallback<<<NTOK / 16, 128, 0, stream>>>(x, W, b, out);
    }
}